// Round 1
// baseline (232.442 us; speedup 1.0000x reference)
//
#include <hip/hip_runtime.h>

typedef unsigned short u16;
typedef __attribute__((ext_vector_type(8))) short short8;
typedef __attribute__((ext_vector_type(4))) float f32x4;

#define B_ 4
#define L_ 4096
#define D_ 1024
#define S_ 16
#define M_ (B_ * L_)   // 16384 rows

__device__ __forceinline__ float b2f(u16 h) {
    unsigned u = ((unsigned)h) << 16;
    return __builtin_bit_cast(float, u);
}
__device__ __forceinline__ u16 f2b(float f) {
    unsigned u = __builtin_bit_cast(unsigned, f);
    u += 0x7fffu + ((u >> 16) & 1u);   // RNE
    return (u16)(u >> 16);
}
__device__ __forceinline__ float softplus_f(float z) {
    return z > 20.f ? z : log1pf(__expf(z));
}

// ---------------- weight transpose: W[k][n] fp32 -> Wt[n][k] bf16 ----------------
__global__ __launch_bounds__(256) void transpose_to_bf16(
    const float* __restrict__ W, u16* __restrict__ Wt, int D) {
    __shared__ float t[32][33];
    int bx = blockIdx.x, by = blockIdx.y;
    int x = threadIdx.x;
    for (int j = threadIdx.y; j < 32; j += 8)
        t[j][x] = W[(size_t)(by * 32 + j) * D + bx * 32 + x];
    __syncthreads();
    for (int j = threadIdx.y; j < 32; j += 8)
        Wt[(size_t)(bx * 32 + j) * D + by * 32 + x] = f2b(t[x][j]);
}

// ---------------- pack projection weights: Wp[s][k], s: 0-15 A, 16-31 B, 32-47 C, 48 dt, 49 = 1/D ----------------
__global__ __launch_bounds__(256) void pack_wp(
    const float* __restrict__ WA, const float* __restrict__ WB,
    const float* __restrict__ WC, const float* __restrict__ Wdt,
    u16* __restrict__ Wp) {
    int idx = blockIdx.x * 256 + threadIdx.x;   // 0..65535
    int s = idx >> 10, k = idx & 1023;
    float v;
    if (s < 16)       v = WA[k * 16 + s];
    else if (s < 32)  v = WB[k * 16 + (s - 16)];
    else if (s < 48)  v = WC[k * 16 + (s - 32)];
    else if (s == 48) v = Wdt[k];
    else if (s == 49) v = 1.0f / 1024.0f;
    else              v = 0.f;
    Wp[idx] = f2b(v);
}

// ---------------- LayerNorm: fp32 in -> bf16 out ----------------
__global__ __launch_bounds__(256) void ln_kernel(
    const float* __restrict__ x, const float* __restrict__ gamma,
    const float* __restrict__ beta, u16* __restrict__ out) {
    int row = blockIdx.x, tid = threadIdx.x;
    const float4 v = *(const float4*)&x[(size_t)row * D_ + tid * 4];
    float s = v.x + v.y + v.z + v.w;
    float q = v.x * v.x + v.y * v.y + v.z * v.z + v.w * v.w;
    for (int o = 32; o > 0; o >>= 1) { s += __shfl_down(s, o); q += __shfl_down(q, o); }
    __shared__ float ss[4], qq[4];
    int w = tid >> 6, lane = tid & 63;
    if (lane == 0) { ss[w] = s; qq[w] = q; }
    __syncthreads();
    if (tid == 0) {
        float S = ss[0] + ss[1] + ss[2] + ss[3];
        float Q = qq[0] + qq[1] + qq[2] + qq[3];
        float mu = S * (1.f / D_);
        float var = Q * (1.f / D_) - mu * mu;
        ss[0] = mu; qq[0] = rsqrtf(var + 1e-5f);
    }
    __syncthreads();
    float mu = ss[0], rs = qq[0];
    const float4 gv = *(const float4*)&gamma[tid * 4];
    const float4 bv = *(const float4*)&beta[tid * 4];
    ushort4 o4;
    o4.x = f2b((v.x - mu) * rs * gv.x + bv.x);
    o4.y = f2b((v.y - mu) * rs * gv.y + bv.y);
    o4.z = f2b((v.z - mu) * rs * gv.z + bv.z);
    o4.w = f2b((v.w - mu) * rs * gv.w + bv.w);
    *(ushort4*)&out[(size_t)row * D_ + tid * 4] = o4;
}

// ---------------- main GEMM: C = A[M,K] * Bt[N,K]^T, bf16 MFMA 16x16x32 ----------------
// EPI==1: out = silu(acc + bias) -> bf16     EPI==2: out = acc + bias + resid -> fp32
template <int EPI>
__global__ __launch_bounds__(256) void gemm_bt(
    const u16* __restrict__ A, const u16* __restrict__ Bt,
    const float* __restrict__ bias, const float* __restrict__ resid,
    u16* __restrict__ outB, float* __restrict__ outF,
    int M, int N, int K, int nTileN) {
    __shared__ u16 As[128][32];
    __shared__ u16 Bs[128][32];
    int bx = blockIdx.x % nTileN, by = blockIdx.x / nTileN;
    int rowBase = by * 128, colBase = bx * 128;
    int tid = threadIdx.x;
    int lane = tid & 63, w = tid >> 6;
    int wm = (w >> 1) * 64, wn = (w & 1) * 64;
    int lr = lane & 15, lg = lane >> 4;
    f32x4 acc[4][4] = {};
    int r0 = tid >> 2, c0 = (tid & 3) * 8;
    for (int k0 = 0; k0 < K; k0 += 32) {
        *(uint4*)&As[r0][c0]      = *(const uint4*)&A[(size_t)(rowBase + r0) * K + k0 + c0];
        *(uint4*)&As[r0 + 64][c0] = *(const uint4*)&A[(size_t)(rowBase + r0 + 64) * K + k0 + c0];
        *(uint4*)&Bs[r0][c0]      = *(const uint4*)&Bt[(size_t)(colBase + r0) * K + k0 + c0];
        *(uint4*)&Bs[r0 + 64][c0] = *(const uint4*)&Bt[(size_t)(colBase + r0 + 64) * K + k0 + c0];
        __syncthreads();
        short8 a[4], b[4];
#pragma unroll
        for (int m = 0; m < 4; m++) a[m] = *(const short8*)&As[wm + m * 16 + lr][lg * 8];
#pragma unroll
        for (int n = 0; n < 4; n++) b[n] = *(const short8*)&Bs[wn + n * 16 + lr][lg * 8];
#pragma unroll
        for (int m = 0; m < 4; m++)
#pragma unroll
            for (int n = 0; n < 4; n++)
                acc[m][n] = __builtin_amdgcn_mfma_f32_16x16x32_bf16(a[m], b[n], acc[m][n], 0, 0, 0);
        __syncthreads();
    }
#pragma unroll
    for (int m = 0; m < 4; m++)
#pragma unroll
        for (int n = 0; n < 4; n++)
#pragma unroll
            for (int j = 0; j < 4; j++) {
                int row = rowBase + wm + m * 16 + lg * 4 + j;
                int col = colBase + wn + n * 16 + lr;
                float v = acc[m][n][j] + bias[col];
                size_t o = (size_t)row * N + col;
                if (EPI == 1) {
                    v = v / (1.f + __expf(-v));     // silu
                    outB[o] = f2b(v);
                } else {
                    outF[o] = v + resid[o];
                }
            }
}

// ---------------- projection GEMM: X[M,1024] x Wp[64,1024]^T -> A_disc, Bu, C_t ----------------
__global__ __launch_bounds__(256) void proj_kernel(
    const u16* __restrict__ X, const u16* __restrict__ Wp,
    const float* __restrict__ bA, const float* __restrict__ bB,
    const float* __restrict__ bC, const float* __restrict__ bdt,
    float* __restrict__ Ad, float* __restrict__ Bu, float* __restrict__ Ct) {
    __shared__ u16 Xs[64][32];
    __shared__ u16 Ws[64][32];
    int rowBase = blockIdx.x * 64;
    int tid = threadIdx.x, lane = tid & 63, w = tid >> 6;
    int lr = lane & 15, lg = lane >> 4;
    f32x4 acc[4] = {};
    int r0 = tid >> 2, c0 = (tid & 3) * 8;
    for (int k0 = 0; k0 < 1024; k0 += 32) {
        *(uint4*)&Xs[r0][c0] = *(const uint4*)&X[(size_t)(rowBase + r0) * 1024 + k0 + c0];
        *(uint4*)&Ws[r0][c0] = *(const uint4*)&Wp[(size_t)r0 * 1024 + k0 + c0];
        __syncthreads();
        short8 a = *(const short8*)&Xs[w * 16 + lr][lg * 8];
#pragma unroll
        for (int n = 0; n < 4; n++) {
            short8 b = *(const short8*)&Ws[n * 16 + lr][lg * 8];
            acc[n] = __builtin_amdgcn_mfma_f32_16x16x32_bf16(a, b, acc[n], 0, 0, 0);
        }
        __syncthreads();
    }
    float bdt0 = bdt[0];
#pragma unroll
    for (int j = 0; j < 4; j++) {
        int row = rowBase + w * 16 + lg * 4 + j;
        float dtr = __shfl(acc[3][j], lg * 16 + 0, 64);   // col 48 = z_dt
        float uv  = __shfl(acc[3][j], lg * 16 + 1, 64);   // col 49 = u (mean)
        float dt = softplus_f(dtr + bdt0);
        float zA = acc[0][j] + bA[lr];
        float zB = acc[1][j] + bB[lr];
        float zC = acc[2][j] + bC[lr];
        size_t o = (size_t)row * 16 + lr;
        Ad[o] = __expf(-dt * softplus_f(zA));
        Bu[o] = zB * dt * uv;
        Ct[o] = zC;
    }
}

// ---------------- chunked parallel scan + y = sum_s(C*h) ----------------
__global__ __launch_bounds__(1024) void scan_kernel(
    const float* __restrict__ Ad, const float* __restrict__ Bu,
    const float* __restrict__ Ct, const float* __restrict__ hprev,
    float* __restrict__ y, float* __restrict__ hfinal) {
    int b = blockIdx.x;
    int tid = threadIdx.x;
    int s = tid & 15, c = tid >> 4;   // c in 0..63, 64 steps each
    const size_t base = (size_t)b * L_ * S_;
    float P = 1.f, Q = 0.f;
    for (int i = 0; i < 64; i++) {
        size_t idx = base + (size_t)(c * 64 + i) * S_ + s;
        float a = Ad[idx], bu = Bu[idx];
        P = a * P;
        Q = a * Q + bu;
    }
    __shared__ float Ps[16][64], Qs[16][64], Hin[16][65];
    Ps[s][c] = P; Qs[s][c] = Q;
    __syncthreads();
    if (tid < 16) {
        float h = hprev[b * S_ + tid];
        for (int cc = 0; cc < 64; cc++) {
            Hin[tid][cc] = h;
            h = Ps[tid][cc] * h + Qs[tid][cc];
        }
        hfinal[b * S_ + tid] = h;
    }
    __syncthreads();
    float h = Hin[s][c];
    for (int i = 0; i < 64; i++) {
        size_t idx = base + (size_t)(c * 64 + i) * S_ + s;
        h = Ad[idx] * h + Bu[idx];
        float p = Ct[idx] * h;
        p += __shfl_xor(p, 1);
        p += __shfl_xor(p, 2);
        p += __shfl_xor(p, 4);
        p += __shfl_xor(p, 8);
        if (s == 0) y[(size_t)b * L_ + c * 64 + i] = p;
    }
}

// ---------------- z = x * y (row broadcast), bf16 ----------------
__global__ __launch_bounds__(256) void scale_kernel(
    const u16* __restrict__ X, const float* __restrict__ y, u16* __restrict__ Z) {
    size_t i = ((size_t)blockIdx.x * 256 + threadIdx.x) * 8;
    float yv = y[i >> 10];
    union { uint4 u; u16 s[8]; } in, out;
    in.u = *(const uint4*)&X[i];
#pragma unroll
    for (int j = 0; j < 8; j++) out.s[j] = f2b(b2f(in.s[j]) * yv);
    *(uint4*)&Z[i] = out.u;
}

extern "C" void kernel_launch(void* const* d_in, const int* in_sizes, int n_in,
                              void* d_out, int out_size, void* d_ws, size_t ws_size,
                              hipStream_t stream) {
    const float* x_seq  = (const float*)d_in[0];
    const float* h_prev = (const float*)d_in[1];
    const float* gamma  = (const float*)d_in[2];
    const float* beta   = (const float*)d_in[3];
    const float* W_in   = (const float*)d_in[4];
    const float* b_in   = (const float*)d_in[5];
    const float* W_A    = (const float*)d_in[6];
    const float* b_A    = (const float*)d_in[7];
    const float* W_B    = (const float*)d_in[8];
    const float* b_B    = (const float*)d_in[9];
    const float* W_C    = (const float*)d_in[10];
    const float* b_C    = (const float*)d_in[11];
    const float* W_dt   = (const float*)d_in[12];
    const float* b_dt   = (const float*)d_in[13];
    const float* W_out  = (const float*)d_in[14];
    const float* b_out  = (const float*)d_in[15];

    char* ws = (char*)d_ws;
    u16*   x_ln   = (u16*)(ws + 0);          // 33554432 B (reused as z later)
    u16*   x      = (u16*)(ws + 33554432);   // 33554432 B
    u16*   Wt_in  = (u16*)(ws + 67108864);   // 2097152 B
    u16*   Wt_out = (u16*)(ws + 69206016);   // 2097152 B
    u16*   Wp     = (u16*)(ws + 71303168);   // 131072 B
    float* Ad     = (float*)(ws + 71434240); // 1048576 B
    float* Bu     = (float*)(ws + 72482816); // 1048576 B
    float* Ct     = (float*)(ws + 73531392); // 1048576 B
    float* yv     = (float*)(ws + 74579968); // 65536 B
    u16*   z      = x_ln;                    // reuse (x_ln dead after GEMM1)
    float* out    = (float*)d_out;

    transpose_to_bf16<<<dim3(32, 32), dim3(32, 8), 0, stream>>>(W_in, Wt_in, D_);
    transpose_to_bf16<<<dim3(32, 32), dim3(32, 8), 0, stream>>>(W_out, Wt_out, D_);
    pack_wp<<<256, 256, 0, stream>>>(W_A, W_B, W_C, W_dt, Wp);
    ln_kernel<<<M_, 256, 0, stream>>>(x_seq, gamma, beta, x_ln);
    gemm_bt<1><<<(M_ / 128) * (D_ / 128), 256, 0, stream>>>(
        x_ln, Wt_in, b_in, nullptr, x, nullptr, M_, D_, D_, D_ / 128);
    proj_kernel<<<M_ / 64, 256, 0, stream>>>(x, Wp, b_A, b_B, b_C, b_dt, Ad, Bu, Ct);
    scan_kernel<<<B_, 1024, 0, stream>>>(Ad, Bu, Ct, h_prev, yv, out + (size_t)M_ * D_);
    scale_kernel<<<(M_ * D_ / 8) / 256, 256, 0, stream>>>(x, yv, z);
    gemm_bt<2><<<(M_ / 128) * (D_ / 128), 256, 0, stream>>>(
        z, Wt_out, b_out, x_seq, nullptr, out, M_, D_, D_, D_ / 128);
}

// Round 2
// 210.103 us; speedup vs baseline: 1.1063x; 1.1063x over previous
//
#include <hip/hip_runtime.h>

typedef unsigned short u16;
typedef unsigned int u32;
typedef __attribute__((ext_vector_type(8))) short short8;
typedef __attribute__((ext_vector_type(4))) float f32x4;

#define B_ 4
#define L_ 4096
#define D_ 1024
#define S_ 16
#define M_ (B_ * L_)   // 16384 rows

__device__ __forceinline__ float b2f(u16 h) {
    unsigned u = ((unsigned)h) << 16;
    return __builtin_bit_cast(float, u);
}
__device__ __forceinline__ u16 f2b(float f) {
    unsigned u = __builtin_bit_cast(unsigned, f);
    u += 0x7fffu + ((u >> 16) & 1u);   // RNE
    return (u16)(u >> 16);
}
__device__ __forceinline__ float softplus_f(float z) {
    return z > 20.f ? z : log1pf(__expf(z));
}
__device__ __forceinline__ void gload16(const u16* g, u16* l) {
    __builtin_amdgcn_global_load_lds(
        (const __attribute__((address_space(1))) u32*)g,
        (__attribute__((address_space(3))) u32*)l, 16, 0, 0);
}

// ---------------- weight transpose: W[k][n] fp32 -> Wt[n][k] bf16 ----------------
__global__ __launch_bounds__(256) void transpose_to_bf16(
    const float* __restrict__ W, u16* __restrict__ Wt, int D) {
    __shared__ float t[32][33];
    int bx = blockIdx.x, by = blockIdx.y;
    int x = threadIdx.x;
    for (int j = threadIdx.y; j < 32; j += 8)
        t[j][x] = W[(size_t)(by * 32 + j) * D + bx * 32 + x];
    __syncthreads();
    for (int j = threadIdx.y; j < 32; j += 8)
        Wt[(size_t)(bx * 32 + j) * D + by * 32 + x] = f2b(t[x][j]);
}

// ---------------- pack projection weights: Wp[s][k], s: 0-15 A, 16-31 B, 32-47 C, 48 dt, 49 = 1/D ----------------
__global__ __launch_bounds__(256) void pack_wp(
    const float* __restrict__ WA, const float* __restrict__ WB,
    const float* __restrict__ WC, const float* __restrict__ Wdt,
    u16* __restrict__ Wp) {
    int idx = blockIdx.x * 256 + threadIdx.x;   // 0..65535
    int s = idx >> 10, k = idx & 1023;
    float v;
    if (s < 16)       v = WA[k * 16 + s];
    else if (s < 32)  v = WB[k * 16 + (s - 16)];
    else if (s < 48)  v = WC[k * 16 + (s - 32)];
    else if (s == 48) v = Wdt[k];
    else if (s == 49) v = 1.0f / 1024.0f;
    else              v = 0.f;
    Wp[idx] = f2b(v);
}

// ---------------- LayerNorm: fp32 in -> bf16 out ----------------
__global__ __launch_bounds__(256) void ln_kernel(
    const float* __restrict__ x, const float* __restrict__ gamma,
    const float* __restrict__ beta, u16* __restrict__ out) {
    int row = blockIdx.x, tid = threadIdx.x;
    const float4 v = *(const float4*)&x[(size_t)row * D_ + tid * 4];
    float s = v.x + v.y + v.z + v.w;
    float q = v.x * v.x + v.y * v.y + v.z * v.z + v.w * v.w;
    for (int o = 32; o > 0; o >>= 1) { s += __shfl_down(s, o); q += __shfl_down(q, o); }
    __shared__ float ss[4], qq[4];
    int w = tid >> 6, lane = tid & 63;
    if (lane == 0) { ss[w] = s; qq[w] = q; }
    __syncthreads();
    if (tid == 0) {
        float S = ss[0] + ss[1] + ss[2] + ss[3];
        float Q = qq[0] + qq[1] + qq[2] + qq[3];
        float mu = S * (1.f / D_);
        float var = Q * (1.f / D_) - mu * mu;
        ss[0] = mu; qq[0] = rsqrtf(var + 1e-5f);
    }
    __syncthreads();
    float mu = ss[0], rs = qq[0];
    const float4 gv = *(const float4*)&gamma[tid * 4];
    const float4 bv = *(const float4*)&beta[tid * 4];
    ushort4 o4;
    o4.x = f2b((v.x - mu) * rs * gv.x + bv.x);
    o4.y = f2b((v.y - mu) * rs * gv.y + bv.y);
    o4.z = f2b((v.z - mu) * rs * gv.z + bv.z);
    o4.w = f2b((v.w - mu) * rs * gv.w + bv.w);
    *(ushort4*)&out[(size_t)row * D_ + tid * 4] = o4;
}

// ---------------- main GEMM: C = A[M,K] * Bt[N,K]^T, bf16 MFMA 16x16x32 ----------------
// m97 structure: global_load_lds width-16 staging, 128x128 tile, 4 waves, 4x4 frags.
// EPI==1: out = silu(acc + bias) -> bf16
// EPI==2: out = yrow[row]*acc + bias + resid -> fp32   (y folded into epilogue)
template <int EPI>
__global__ __launch_bounds__(256) void gemm_bt(
    const u16* __restrict__ A, const u16* __restrict__ Bt,
    const float* __restrict__ bias, const float* __restrict__ resid,
    const float* __restrict__ yrow,
    u16* __restrict__ outB, float* __restrict__ outF,
    int M, int N, int K, int nTileN) {
    __shared__ u16 As[128][32];
    __shared__ u16 Bs[128][32];
    // XCD-aware swizzle (grid % 8 == 0): contiguous chunk per XCD -> A panels L2-resident
    int nwg = gridDim.x;
    int bid = blockIdx.x;
    int swz = (bid & 7) * (nwg >> 3) + (bid >> 3);
    int bx = swz % nTileN, by = swz / nTileN;
    int rowBase = by * 128, colBase = bx * 128;
    int tid = threadIdx.x;
    int lane = tid & 63, w = tid >> 6;
    int wm = (w >> 1) * 64, wn = (w & 1) * 64;
    int lr = lane & 15, lg = lane >> 4;
    f32x4 acc[4][4] = {};

    // staging addresses: wave w owns rows [w*32, w*32+32) of each tile,
    // 2 x global_load_lds_dwordx4 per wave per tile (16 rows each, linear LDS)
    const int sr = lane >> 2;            // 0..15 row within 16-row group
    const int sc = (lane & 3) * 8;       // element col (16B chunks)
    const u16* gA = &A[(size_t)(rowBase + w * 32 + sr) * K + sc];
    const u16* gB = &Bt[(size_t)(colBase + w * 32 + sr) * K + sc];
    u16* lA0 = &As[w * 32][0];
    u16* lA1 = &As[w * 32 + 16][0];
    u16* lB0 = &Bs[w * 32][0];
    u16* lB1 = &Bs[w * 32 + 16][0];
    const size_t rowK16 = (size_t)16 * K;

    for (int k0 = 0; k0 < K; k0 += 32) {
        gload16(gA + k0, lA0);
        gload16(gA + rowK16 + k0, lA1);
        gload16(gB + k0, lB0);
        gload16(gB + rowK16 + k0, lB1);
        __syncthreads();            // drains vmcnt(0): staged tile visible
        short8 a[4], b[4];
#pragma unroll
        for (int m = 0; m < 4; m++) a[m] = *(const short8*)&As[wm + m * 16 + lr][lg * 8];
#pragma unroll
        for (int n = 0; n < 4; n++) b[n] = *(const short8*)&Bs[wn + n * 16 + lr][lg * 8];
#pragma unroll
        for (int m = 0; m < 4; m++)
#pragma unroll
            for (int n = 0; n < 4; n++)
                acc[m][n] = __builtin_amdgcn_mfma_f32_16x16x32_bf16(a[m], b[n], acc[m][n], 0, 0, 0);
        __syncthreads();            // all waves done reading before restage
    }
#pragma unroll
    for (int m = 0; m < 4; m++) {
        float yr[4];
        if (EPI == 2) {
#pragma unroll
            for (int j = 0; j < 4; j++) yr[j] = yrow[rowBase + wm + m * 16 + lg * 4 + j];
        }
#pragma unroll
        for (int n = 0; n < 4; n++)
#pragma unroll
            for (int j = 0; j < 4; j++) {
                int row = rowBase + wm + m * 16 + lg * 4 + j;
                int col = colBase + wn + n * 16 + lr;
                size_t o = (size_t)row * N + col;
                if (EPI == 1) {
                    float v = acc[m][n][j] + bias[col];
                    v = v / (1.f + __expf(-v));     // silu
                    outB[o] = f2b(v);
                } else {
                    outF[o] = acc[m][n][j] * yr[j] + bias[col] + resid[o];
                }
            }
    }
}

// ---------------- projection GEMM: X[M,1024] x Wp[64,1024]^T -> A_disc, Bu, C_t ----------------
__global__ __launch_bounds__(256) void proj_kernel(
    const u16* __restrict__ X, const u16* __restrict__ Wp,
    const float* __restrict__ bA, const float* __restrict__ bB,
    const float* __restrict__ bC, const float* __restrict__ bdt,
    float* __restrict__ Ad, float* __restrict__ Bu, float* __restrict__ Ct) {
    __shared__ u16 Xs[64][32];
    __shared__ u16 Ws[64][32];
    int rowBase = blockIdx.x * 64;
    int tid = threadIdx.x, lane = tid & 63, w = tid >> 6;
    int lr = lane & 15, lg = lane >> 4;
    f32x4 acc[4] = {};
    int r0 = tid >> 2, c0 = (tid & 3) * 8;
    for (int k0 = 0; k0 < 1024; k0 += 32) {
        *(uint4*)&Xs[r0][c0] = *(const uint4*)&X[(size_t)(rowBase + r0) * 1024 + k0 + c0];
        *(uint4*)&Ws[r0][c0] = *(const uint4*)&Wp[(size_t)r0 * 1024 + k0 + c0];
        __syncthreads();
        short8 a = *(const short8*)&Xs[w * 16 + lr][lg * 8];
#pragma unroll
        for (int n = 0; n < 4; n++) {
            short8 b = *(const short8*)&Ws[n * 16 + lr][lg * 8];
            acc[n] = __builtin_amdgcn_mfma_f32_16x16x32_bf16(a, b, acc[n], 0, 0, 0);
        }
        __syncthreads();
    }
    float bdt0 = bdt[0];
#pragma unroll
    for (int j = 0; j < 4; j++) {
        int row = rowBase + w * 16 + lg * 4 + j;
        float dtr = __shfl(acc[3][j], lg * 16 + 0, 64);   // col 48 = z_dt
        float uv  = __shfl(acc[3][j], lg * 16 + 1, 64);   // col 49 = u (mean)
        float dt = softplus_f(dtr + bdt0);
        float zA = acc[0][j] + bA[lr];
        float zB = acc[1][j] + bB[lr];
        float zC = acc[2][j] + bC[lr];
        size_t o = (size_t)row * 16 + lr;
        Ad[o] = __expf(-dt * softplus_f(zA));
        Bu[o] = zB * dt * uv;
        Ct[o] = zC;
    }
}

// ---------------- chunked parallel scan + y = sum_s(C*h) ----------------
__global__ __launch_bounds__(1024) void scan_kernel(
    const float* __restrict__ Ad, const float* __restrict__ Bu,
    const float* __restrict__ Ct, const float* __restrict__ hprev,
    float* __restrict__ y, float* __restrict__ hfinal) {
    int b = blockIdx.x;
    int tid = threadIdx.x;
    int s = tid & 15, c = tid >> 4;   // c in 0..63, 64 steps each
    const size_t base = (size_t)b * L_ * S_;
    float P = 1.f, Q = 0.f;
    for (int i = 0; i < 64; i++) {
        size_t idx = base + (size_t)(c * 64 + i) * S_ + s;
        float a = Ad[idx], bu = Bu[idx];
        P = a * P;
        Q = a * Q + bu;
    }
    __shared__ float Ps[16][64], Qs[16][64], Hin[16][65];
    Ps[s][c] = P; Qs[s][c] = Q;
    __syncthreads();
    if (tid < 16) {
        float h = hprev[b * S_ + tid];
        for (int cc = 0; cc < 64; cc++) {
            Hin[tid][cc] = h;
            h = Ps[tid][cc] * h + Qs[tid][cc];
        }
        hfinal[b * S_ + tid] = h;
    }
    __syncthreads();
    float h = Hin[s][c];
    for (int i = 0; i < 64; i++) {
        size_t idx = base + (size_t)(c * 64 + i) * S_ + s;
        h = Ad[idx] * h + Bu[idx];
        float p = Ct[idx] * h;
        p += __shfl_xor(p, 1);
        p += __shfl_xor(p, 2);
        p += __shfl_xor(p, 4);
        p += __shfl_xor(p, 8);
        if (s == 0) y[(size_t)b * L_ + c * 64 + i] = p;
    }
}

extern "C" void kernel_launch(void* const* d_in, const int* in_sizes, int n_in,
                              void* d_out, int out_size, void* d_ws, size_t ws_size,
                              hipStream_t stream) {
    const float* x_seq  = (const float*)d_in[0];
    const float* h_prev = (const float*)d_in[1];
    const float* gamma  = (const float*)d_in[2];
    const float* beta   = (const float*)d_in[3];
    const float* W_in   = (const float*)d_in[4];
    const float* b_in   = (const float*)d_in[5];
    const float* W_A    = (const float*)d_in[6];
    const float* b_A    = (const float*)d_in[7];
    const float* W_B    = (const float*)d_in[8];
    const float* b_B    = (const float*)d_in[9];
    const float* W_C    = (const float*)d_in[10];
    const float* b_C    = (const float*)d_in[11];
    const float* W_dt   = (const float*)d_in[12];
    const float* b_dt   = (const float*)d_in[13];
    const float* W_out  = (const float*)d_in[14];
    const float* b_out  = (const float*)d_in[15];

    char* ws = (char*)d_ws;
    u16*   x_ln   = (u16*)(ws + 0);          // 33554432 B
    u16*   x      = (u16*)(ws + 33554432);   // 33554432 B
    u16*   Wt_in  = (u16*)(ws + 67108864);   // 2097152 B
    u16*   Wt_out = (u16*)(ws + 69206016);   // 2097152 B
    u16*   Wp     = (u16*)(ws + 71303168);   // 131072 B
    float* Ad     = (float*)(ws + 71434240); // 1048576 B
    float* Bu     = (float*)(ws + 72482816); // 1048576 B
    float* Ct     = (float*)(ws + 73531392); // 1048576 B
    float* yv     = (float*)(ws + 74579968); // 65536 B
    float* out    = (float*)d_out;

    transpose_to_bf16<<<dim3(32, 32), dim3(32, 8), 0, stream>>>(W_in, Wt_in, D_);
    transpose_to_bf16<<<dim3(32, 32), dim3(32, 8), 0, stream>>>(W_out, Wt_out, D_);
    pack_wp<<<256, 256, 0, stream>>>(W_A, W_B, W_C, W_dt, Wp);
    ln_kernel<<<M_, 256, 0, stream>>>(x_seq, gamma, beta, x_ln);
    gemm_bt<1><<<(M_ / 128) * (D_ / 128), 256, 0, stream>>>(
        x_ln, Wt_in, b_in, nullptr, nullptr, x, nullptr, M_, D_, D_, D_ / 128);
    proj_kernel<<<M_ / 64, 256, 0, stream>>>(x, Wp, b_A, b_B, b_C, b_dt, Ad, Bu, Ct);
    scan_kernel<<<B_, 1024, 0, stream>>>(Ad, Bu, Ct, h_prev, yv, out + (size_t)M_ * D_);
    gemm_bt<2><<<(M_ / 128) * (D_ / 128), 256, 0, stream>>>(
        x, Wt_out, b_out, x_seq, yv, nullptr, out, M_, D_, D_, D_ / 128);
}

// Round 3
// 200.801 us; speedup vs baseline: 1.1576x; 1.0463x over previous
//
#include <hip/hip_runtime.h>

typedef unsigned short u16;
typedef unsigned int u32;
typedef __attribute__((ext_vector_type(8))) short short8;
typedef __attribute__((ext_vector_type(4))) float f32x4;

#define B_ 4
#define L_ 4096
#define D_ 1024
#define S_ 16
#define M_ (B_ * L_)   // 16384 rows

__device__ __forceinline__ float b2f(u16 h) {
    unsigned u = ((unsigned)h) << 16;
    return __builtin_bit_cast(float, u);
}
__device__ __forceinline__ u16 f2b(float f) {
    unsigned u = __builtin_bit_cast(unsigned, f);
    u += 0x7fffu + ((u >> 16) & 1u);   // RNE
    return (u16)(u >> 16);
}
__device__ __forceinline__ float softplus_f(float z) {
    return z > 20.f ? z : log1pf(__expf(z));
}
__device__ __forceinline__ void gload16(const u16* g, u16* l) {
    __builtin_amdgcn_global_load_lds(
        (const __attribute__((address_space(1))) u32*)g,
        (__attribute__((address_space(3))) u32*)l, 16, 0, 0);
}

// ---------------- weight transpose: W[k][n] fp32 -> Wt[n][k] bf16 (z picks which W) ----------------
__global__ __launch_bounds__(256) void transpose_to_bf16(
    const float* __restrict__ W0, u16* __restrict__ Wt0,
    const float* __restrict__ W1, u16* __restrict__ Wt1) {
    const float* W = blockIdx.z ? W1 : W0;
    u16* Wt = blockIdx.z ? Wt1 : Wt0;
    __shared__ float t[32][33];
    int bx = blockIdx.x, by = blockIdx.y;
    int x = threadIdx.x;
    for (int j = threadIdx.y; j < 32; j += 8)
        t[j][x] = W[(size_t)(by * 32 + j) * D_ + bx * 32 + x];
    __syncthreads();
    for (int j = threadIdx.y; j < 32; j += 8)
        Wt[(size_t)(bx * 32 + j) * D_ + by * 32 + x] = f2b(t[x][j]);
}

// ---------------- pack projection weights: Wp[s][k], s: 0-15 A, 16-31 B, 32-47 C, 48 dt, 49 = 1/D ----------------
__global__ __launch_bounds__(256) void pack_wp(
    const float* __restrict__ WA, const float* __restrict__ WB,
    const float* __restrict__ WC, const float* __restrict__ Wdt,
    u16* __restrict__ Wp) {
    int idx = blockIdx.x * 256 + threadIdx.x;   // 0..65535
    int s = idx >> 10, k = idx & 1023;
    float v;
    if (s < 16)       v = WA[k * 16 + s];
    else if (s < 32)  v = WB[k * 16 + (s - 16)];
    else if (s < 48)  v = WC[k * 16 + (s - 32)];
    else if (s == 48) v = Wdt[k];
    else if (s == 49) v = 1.0f / 1024.0f;
    else              v = 0.f;
    Wp[idx] = f2b(v);
}

// ---------------- LayerNorm: fp32 in -> bf16 out ----------------
__global__ __launch_bounds__(256) void ln_kernel(
    const float* __restrict__ x, const float* __restrict__ gamma,
    const float* __restrict__ beta, u16* __restrict__ out) {
    int row = blockIdx.x, tid = threadIdx.x;
    const float4 v = *(const float4*)&x[(size_t)row * D_ + tid * 4];
    float s = v.x + v.y + v.z + v.w;
    float q = v.x * v.x + v.y * v.y + v.z * v.z + v.w * v.w;
    for (int o = 32; o > 0; o >>= 1) { s += __shfl_down(s, o); q += __shfl_down(q, o); }
    __shared__ float ss[4], qq[4];
    int w = tid >> 6, lane = tid & 63;
    if (lane == 0) { ss[w] = s; qq[w] = q; }
    __syncthreads();
    if (tid == 0) {
        float S = ss[0] + ss[1] + ss[2] + ss[3];
        float Q = qq[0] + qq[1] + qq[2] + qq[3];
        float mu = S * (1.f / D_);
        float var = Q * (1.f / D_) - mu * mu;
        ss[0] = mu; qq[0] = rsqrtf(var + 1e-5f);
    }
    __syncthreads();
    float mu = ss[0], rs = qq[0];
    const float4 gv = *(const float4*)&gamma[tid * 4];
    const float4 bv = *(const float4*)&beta[tid * 4];
    ushort4 o4;
    o4.x = f2b((v.x - mu) * rs * gv.x + bv.x);
    o4.y = f2b((v.y - mu) * rs * gv.y + bv.y);
    o4.z = f2b((v.z - mu) * rs * gv.z + bv.z);
    o4.w = f2b((v.w - mu) * rs * gv.w + bv.w);
    *(ushort4*)&out[(size_t)row * D_ + tid * 4] = o4;
}

// ---------------- main GEMM: C = A[M,K] * Bt[N,K]^T, bf16 MFMA 16x16x32 ----------------
// 2-phase double-buffered LDS: STAGE(t+1) issued right after the barrier, so the
// __syncthreads vmcnt(0) drain lands after a full compute phase of overlap.
// EPI==1: out = silu(acc + bias) -> bf16
// EPI==2: out = yrow[row]*acc + bias + resid -> fp32   (y folded into epilogue)
template <int EPI>
__global__ __launch_bounds__(256) void gemm_bt(
    const u16* __restrict__ A, const u16* __restrict__ Bt,
    const float* __restrict__ bias, const float* __restrict__ resid,
    const float* __restrict__ yrow,
    u16* __restrict__ outB, float* __restrict__ outF,
    int M, int N, int K, int nTileN) {
    __shared__ u16 As[2][128][32];
    __shared__ u16 Bs[2][128][32];
    // XCD-aware swizzle (grid % 8 == 0): contiguous chunk per XCD -> A panels L2-resident
    int nwg = gridDim.x;
    int bid = blockIdx.x;
    int swz = (bid & 7) * (nwg >> 3) + (bid >> 3);
    int bx = swz % nTileN, by = swz / nTileN;
    int rowBase = by * 128, colBase = bx * 128;
    int tid = threadIdx.x;
    int lane = tid & 63, w = tid >> 6;
    int wm = (w >> 1) * 64, wn = (w & 1) * 64;
    int lr = lane & 15, lg = lane >> 4;
    f32x4 acc[4][4] = {};

    // staging: wave w owns rows [w*32, w*32+32); 2 x global_load_lds_dwordx4 each
    // for A and B (16 rows per gload16, linear LDS dest = base + lane*16B)
    const int sr = lane >> 2;            // 0..15 row within 16-row group
    const int sc = (lane & 3) * 8;       // element col (16B chunks)
    const u16* gA = &A[(size_t)(rowBase + w * 32 + sr) * K + sc];
    const u16* gB = &Bt[(size_t)(colBase + w * 32 + sr) * K + sc];
    const size_t rowK16 = (size_t)16 * K;

#define STAGE(d, k0)                                   \
    do {                                               \
        gload16(gA + (k0), &As[d][w * 32][0]);         \
        gload16(gA + rowK16 + (k0), &As[d][w * 32 + 16][0]); \
        gload16(gB + (k0), &Bs[d][w * 32][0]);         \
        gload16(gB + rowK16 + (k0), &Bs[d][w * 32 + 16][0]); \
    } while (0)

    STAGE(0, 0);
    __syncthreads();          // drains vmcnt(0): buf0 staged
    int cur = 0;
    for (int k0 = 0; k0 < K; k0 += 32) {
        int knext = k0 + 32;
        if (knext < K) STAGE(cur ^ 1, knext);   // prefetch next tile into other buffer
        short8 a[4], b[4];
#pragma unroll
        for (int m = 0; m < 4; m++) a[m] = *(const short8*)&As[cur][wm + m * 16 + lr][lg * 8];
#pragma unroll
        for (int n = 0; n < 4; n++) b[n] = *(const short8*)&Bs[cur][wn + n * 16 + lr][lg * 8];
#pragma unroll
        for (int m = 0; m < 4; m++)
#pragma unroll
            for (int n = 0; n < 4; n++)
                acc[m][n] = __builtin_amdgcn_mfma_f32_16x16x32_bf16(a[m], b[n], acc[m][n], 0, 0, 0);
        __syncthreads();      // drains vmcnt(0) (prefetch done) + lgkm; one barrier/iter
        cur ^= 1;
    }
#undef STAGE
#pragma unroll
    for (int m = 0; m < 4; m++) {
        float yr[4];
        if (EPI == 2) {
#pragma unroll
            for (int j = 0; j < 4; j++) yr[j] = yrow[rowBase + wm + m * 16 + lg * 4 + j];
        }
#pragma unroll
        for (int n = 0; n < 4; n++)
#pragma unroll
            for (int j = 0; j < 4; j++) {
                int row = rowBase + wm + m * 16 + lg * 4 + j;
                int col = colBase + wn + n * 16 + lr;
                size_t o = (size_t)row * N + col;
                if (EPI == 1) {
                    float v = acc[m][n][j] + bias[col];
                    v = v / (1.f + __expf(-v));     // silu
                    outB[o] = f2b(v);
                } else {
                    outF[o] = acc[m][n][j] * yr[j] + bias[col] + resid[o];
                }
            }
    }
}

// ---------------- projection GEMM: X[M,1024] x Wp[64,1024]^T -> A_disc, Bu, C_t ----------------
__global__ __launch_bounds__(256) void proj_kernel(
    const u16* __restrict__ X, const u16* __restrict__ Wp,
    const float* __restrict__ bA, const float* __restrict__ bB,
    const float* __restrict__ bC, const float* __restrict__ bdt,
    float* __restrict__ Ad, float* __restrict__ Bu, float* __restrict__ Ct) {
    __shared__ u16 Xs[64][32];
    __shared__ u16 Ws[64][32];
    int rowBase = blockIdx.x * 64;
    int tid = threadIdx.x, lane = tid & 63, w = tid >> 6;
    int lr = lane & 15, lg = lane >> 4;
    f32x4 acc[4] = {};
    int r0 = tid >> 2, c0 = (tid & 3) * 8;
    for (int k0 = 0; k0 < 1024; k0 += 32) {
        *(uint4*)&Xs[r0][c0] = *(const uint4*)&X[(size_t)(rowBase + r0) * 1024 + k0 + c0];
        *(uint4*)&Ws[r0][c0] = *(const uint4*)&Wp[(size_t)r0 * 1024 + k0 + c0];
        __syncthreads();
        short8 a = *(const short8*)&Xs[w * 16 + lr][lg * 8];
#pragma unroll
        for (int n = 0; n < 4; n++) {
            short8 b = *(const short8*)&Ws[n * 16 + lr][lg * 8];
            acc[n] = __builtin_amdgcn_mfma_f32_16x16x32_bf16(a, b, acc[n], 0, 0, 0);
        }
        __syncthreads();
    }
    float bdt0 = bdt[0];
#pragma unroll
    for (int j = 0; j < 4; j++) {
        int row = rowBase + w * 16 + lg * 4 + j;
        float dtr = __shfl(acc[3][j], lg * 16 + 0, 64);   // col 48 = z_dt
        float uv  = __shfl(acc[3][j], lg * 16 + 1, 64);   // col 49 = u (mean)
        float dt = softplus_f(dtr + bdt0);
        float zA = acc[0][j] + bA[lr];
        float zB = acc[1][j] + bB[lr];
        float zC = acc[2][j] + bC[lr];
        size_t o = (size_t)row * 16 + lr;
        Ad[o] = __expf(-dt * softplus_f(zA));
        Bu[o] = zB * dt * uv;
        Ct[o] = zC;
    }
}

// ---------------- chunked parallel scan + y = sum_s(C*h) ----------------
__global__ __launch_bounds__(1024) void scan_kernel(
    const float* __restrict__ Ad, const float* __restrict__ Bu,
    const float* __restrict__ Ct, const float* __restrict__ hprev,
    float* __restrict__ y, float* __restrict__ hfinal) {
    int b = blockIdx.x;
    int tid = threadIdx.x;
    int s = tid & 15, c = tid >> 4;   // c in 0..63, 64 steps each
    const size_t base = (size_t)b * L_ * S_;
    float P = 1.f, Q = 0.f;
    for (int i = 0; i < 64; i++) {
        size_t idx = base + (size_t)(c * 64 + i) * S_ + s;
        float a = Ad[idx], bu = Bu[idx];
        P = a * P;
        Q = a * Q + bu;
    }
    __shared__ float Ps[16][64], Qs[16][64], Hin[16][65];
    Ps[s][c] = P; Qs[s][c] = Q;
    __syncthreads();
    if (tid < 16) {
        float h = hprev[b * S_ + tid];
        for (int cc = 0; cc < 64; cc++) {
            Hin[tid][cc] = h;
            h = Ps[tid][cc] * h + Qs[tid][cc];
        }
        hfinal[b * S_ + tid] = h;
    }
    __syncthreads();
    float h = Hin[s][c];
    for (int i = 0; i < 64; i++) {
        size_t idx = base + (size_t)(c * 64 + i) * S_ + s;
        h = Ad[idx] * h + Bu[idx];
        float p = Ct[idx] * h;
        p += __shfl_xor(p, 1);
        p += __shfl_xor(p, 2);
        p += __shfl_xor(p, 4);
        p += __shfl_xor(p, 8);
        if (s == 0) y[(size_t)b * L_ + c * 64 + i] = p;
    }
}

extern "C" void kernel_launch(void* const* d_in, const int* in_sizes, int n_in,
                              void* d_out, int out_size, void* d_ws, size_t ws_size,
                              hipStream_t stream) {
    const float* x_seq  = (const float*)d_in[0];
    const float* h_prev = (const float*)d_in[1];
    const float* gamma  = (const float*)d_in[2];
    const float* beta   = (const float*)d_in[3];
    const float* W_in   = (const float*)d_in[4];
    const float* b_in   = (const float*)d_in[5];
    const float* W_A    = (const float*)d_in[6];
    const float* b_A    = (const float*)d_in[7];
    const float* W_B    = (const float*)d_in[8];
    const float* b_B    = (const float*)d_in[9];
    const float* W_C    = (const float*)d_in[10];
    const float* b_C    = (const float*)d_in[11];
    const float* W_dt   = (const float*)d_in[12];
    const float* b_dt   = (const float*)d_in[13];
    const float* W_out  = (const float*)d_in[14];
    const float* b_out  = (const float*)d_in[15];

    char* ws = (char*)d_ws;
    u16*   x_ln   = (u16*)(ws + 0);          // 33554432 B
    u16*   x      = (u16*)(ws + 33554432);   // 33554432 B
    u16*   Wt_in  = (u16*)(ws + 67108864);   // 2097152 B
    u16*   Wt_out = (u16*)(ws + 69206016);   // 2097152 B
    u16*   Wp     = (u16*)(ws + 71303168);   // 131072 B
    float* Ad     = (float*)(ws + 71434240); // 1048576 B
    float* Bu     = (float*)(ws + 72482816); // 1048576 B
    float* Ct     = (float*)(ws + 73531392); // 1048576 B
    float* yv     = (float*)(ws + 74579968); // 65536 B
    float* out    = (float*)d_out;

    transpose_to_bf16<<<dim3(32, 32, 2), dim3(32, 8), 0, stream>>>(W_in, Wt_in, W_out, Wt_out);
    pack_wp<<<256, 256, 0, stream>>>(W_A, W_B, W_C, W_dt, Wp);
    ln_kernel<<<M_, 256, 0, stream>>>(x_seq, gamma, beta, x_ln);
    gemm_bt<1><<<(M_ / 128) * (D_ / 128), 256, 0, stream>>>(
        x_ln, Wt_in, b_in, nullptr, nullptr, x, nullptr, M_, D_, D_, D_ / 128);
    proj_kernel<<<M_ / 64, 256, 0, stream>>>(x, Wp, b_A, b_B, b_C, b_dt, Ad, Bu, Ct);
    scan_kernel<<<B_, 1024, 0, stream>>>(Ad, Bu, Ct, h_prev, yv, out + (size_t)M_ * D_);
    gemm_bt<2><<<(M_ / 128) * (D_ / 128), 256, 0, stream>>>(
        x, Wt_out, b_out, x_seq, yv, nullptr, out, M_, D_, D_, D_ / 128);
}